// Round 2
// baseline (209.243 us; speedup 1.0000x reference)
//
#include <hip/hip_runtime.h>

#define BATCH  4096
#define NROWS  8192
#define LATENT 2048
#define ZDIM   128
#define PRIORc       0.3f
#define PRIOR_PRIMEc 0.5f

typedef __attribute__((ext_vector_type(8))) short bf16x8;  // 8 bf16 = 4 VGPRs
typedef __attribute__((ext_vector_type(4))) float f32x4;   // MFMA C/D

__device__ inline unsigned short f2bf_rne(float f) {
    unsigned int u = __float_as_uint(f);
    u = u + 0x7fffu + ((u >> 16) & 1u);
    return (unsigned short)(u >> 16);
}

__device__ inline float wave_reduce_sum(float v) {
#pragma unroll
    for (int m = 1; m < 64; m <<= 1) v += __shfl_xor(v, m, 64);
    return v;
}

// ZSCALE = sqrt(2 * log2(e)). Folds BOTH 1/TEMP and the exp->exp2 base change
// into the bf16 fragments: MFMA then yields sim*log2(e), so the sim epilogue
// is a single native v_exp_f32 (exp2) per element.
#define ZSCALE 1.69864464f

// ---------------------------------------------------------------------------
// Prep kernel: fuses the two HBM-independent streams so they share the wire.
//   bids [0,1024):    zprep — one wave per positive pair (r, r+BATCH):
//                     normalize, scale by ZSCALE, cast bf16, store swizzled;
//                     exact fp32 positive logit; exact bf16 diagonal dexp;
//                     zero S_row (folds the memset dispatch).
//   bids [1024,3072): logit GEMV — h_i/h_j @ W^T + b, one wave per row.
//                     No dependency on znb, so it does NOT belong in the sim
//                     kernel: there it held residency slots and starved the
//                     latency-bound sim waves (R1: occupancy 20%, Mfma 12.7%).
// ---------------------------------------------------------------------------
__global__ void k_prep(const float* __restrict__ z_i, const float* __restrict__ z_j,
                       const float* __restrict__ h_i, const float* __restrict__ h_j,
                       const float* __restrict__ W, const float* __restrict__ bb,
                       unsigned short* __restrict__ znb, float* __restrict__ pos,
                       float* __restrict__ dexp, float* __restrict__ S_row,
                       float* __restrict__ logits) {
    int bid = blockIdx.x;
    int wave = threadIdx.x >> 6, lane = threadIdx.x & 63;
    if (bid < 1024) {
        if (threadIdx.x < 8) S_row[bid * 8 + threadIdx.x] = 0.f;
        int r = bid * 4 + wave;               // 0..4095
        int p = r + BATCH;
        float2 a = ((const float2*)(z_i + (size_t)r * ZDIM))[lane];
        float2 c = ((const float2*)(z_j + (size_t)r * ZDIM))[lane];
        float sa = wave_reduce_sum(a.x * a.x + a.y * a.y);
        float sc = wave_reduce_sum(c.x * c.x + c.y * c.y);
        float dd = wave_reduce_sum(a.x * c.x + a.y * c.y);
        float inva = 1.f / fmaxf(sqrtf(sa), 1e-8f);
        float invc = 1.f / fmaxf(sqrtf(sc), 1e-8f);
        if (lane == 0) {
            float pv = 2.0f * dd * inva * invc;   // cos-sim / TEMP, exact fp32
            pos[r] = pv;
            pos[p] = pv;
        }
        int kt = lane >> 4;
        int q  = (lane >> 2) & 3;
        int j  = (lane & 3) * 2;
        int lrow = q * 16;
        float fa = inva * ZSCALE, fc = invc * ZSCALE;
        ushort2 wa; wa.x = f2bf_rne(a.x * fa); wa.y = f2bf_rne(a.y * fa);
        ushort2 wc; wc.x = f2bf_rne(c.x * fc); wc.y = f2bf_rne(c.y * fc);
        {   // row r (from z_i)
            size_t off = ((size_t)((r >> 4) * 4 + kt) * 64 + (lrow + (r & 15))) * 8 + j;
            *(ushort2*)(znb + off) = wa;
        }
        {   // row p (from z_j)
            size_t off = ((size_t)((p >> 4) * 4 + kt) * 64 + (lrow + (p & 15))) * 8 + j;
            *(ushort2*)(znb + off) = wc;
        }
        // diagonal of the bf16 sim matrix, fp32-accumulated like MFMA does
        float ax = __uint_as_float((unsigned)wa.x << 16);
        float ay = __uint_as_float((unsigned)wa.y << 16);
        float cx = __uint_as_float((unsigned)wc.x << 16);
        float cy = __uint_as_float((unsigned)wc.y << 16);
        float da = wave_reduce_sum(ax * ax + ay * ay);
        float dc = wave_reduce_sum(cx * cx + cy * cy);
        if (lane == 0) {
            dexp[r] = __builtin_amdgcn_exp2f(da);
            dexp[p] = __builtin_amdgcn_exp2f(dc);
        }
    } else {
        int r = (bid - 1024) * 4 + wave;      // 0..8191
        const float* h = (r < BATCH) ? (h_i + (size_t)r * LATENT)
                                     : (h_j + (size_t)(r - BATCH) * LATENT);
        const f32x4* h4 = (const f32x4*)h;
        const f32x4* w4 = (const f32x4*)W;
        float s = 0.f;
#pragma unroll
        for (int itr = 0; itr < 8; ++itr) {
            f32x4 av = h4[itr * 64 + lane];
            f32x4 wv = w4[itr * 64 + lane];
            s += av.x * wv.x + av.y * wv.y + av.z * wv.z + av.w * wv.w;
        }
        s = wave_reduce_sum(s);
        if (lane == 0) logits[r] = s + bb[0];
    }
}

// ---------------------------------------------------------------------------
// Sim kernel, PURE: 1024 blocks = exactly 4 blocks/CU (16 waves/CU) of
// homogeneous MFMA+exp work. 128-row stripe x 512-col group per block;
// A frags register-resident; B frags software-pipelined; per-element
// epilogue is ONE v_exp (exp2, log2e folded into fragments) + ONE v_add
// (diagonal subtracted in k_final via dexp).
// ---------------------------------------------------------------------------
__global__ void __launch_bounds__(256, 4) k_sim(
        const unsigned short* __restrict__ znb, float* __restrict__ S_row) {
    int sid = blockIdx.x;
    int lane = threadIdx.x & 63, wave = threadIdx.x >> 6;
    int q = lane >> 4, t = lane & 15;
    int row0 = (sid & 63) * 128 + (wave >> 1) * 64;
    int gA = row0 >> 4;
    const bf16x8* zf = (const bf16x8*)znb;

    bf16x8 a[4][4];
#pragma unroll
    for (int mt = 0; mt < 4; ++mt)
#pragma unroll
        for (int kt = 0; kt < 4; ++kt)
            a[mt][kt] = zf[(size_t)((gA + mt) * 4 + kt) * 64 + lane];

    float s[16];
#pragma unroll
    for (int i = 0; i < 16; ++i) s[i] = 0.f;

    int colbase = (sid >> 6) * 512 + (wave & 1) * 64;
    int cb4 = colbase >> 4;
    bf16x8 b[4];
#pragma unroll
    for (int kt = 0; kt < 4; ++kt)
        b[kt] = zf[(size_t)(cb4 * 4 + kt) * 64 + lane];

#pragma unroll 1
    for (int it = 0; it < 4; ++it) {
#pragma unroll
        for (int nt = 0; nt < 4; ++nt) {
            // prefetch next B fragment group
            bf16x8 bn[4];
            if (!(it == 3 && nt == 3)) {
                int ng = cb4 + (nt == 3 ? (it + 1) * 8 : it * 8 + nt + 1);
#pragma unroll
                for (int kt = 0; kt < 4; ++kt)
                    bn[kt] = zf[(size_t)(ng * 4 + kt) * 64 + lane];
            }
            f32x4 acc[4];
            f32x4 zero = {0.f, 0.f, 0.f, 0.f};
#pragma unroll
            for (int mt = 0; mt < 4; ++mt) acc[mt] = zero;
#pragma unroll
            for (int kt = 0; kt < 4; ++kt)
#pragma unroll
                for (int mt = 0; mt < 4; ++mt)
                    acc[mt] = __builtin_amdgcn_mfma_f32_16x16x32_bf16(a[mt][kt], b[kt], acc[mt], 0, 0, 0);
#pragma unroll
            for (int mt = 0; mt < 4; ++mt)
#pragma unroll
                for (int reg = 0; reg < 4; ++reg)
                    s[mt * 4 + reg] += __builtin_amdgcn_exp2f(acc[mt][reg]);
#pragma unroll
            for (int kt = 0; kt < 4; ++kt) b[kt] = bn[kt];
        }
    }
#pragma unroll
    for (int i = 0; i < 16; ++i) {
        float v = s[i];
        v += __shfl_xor(v, 1, 64);
        v += __shfl_xor(v, 2, 64);
        v += __shfl_xor(v, 4, 64);
        v += __shfl_xor(v, 8, 64);
        if (t == 0) atomicAdd(&S_row[row0 + (i >> 2) * 16 + q * 4 + (i & 3)], v);
    }
}

// Single block: nnPU risk from logits+target, NT-Xent sum from
// S_row (minus exact diagonal dexp) + pos, weighted combine.
__global__ void k_final(const float* __restrict__ S_row, const float* __restrict__ pos,
                        const float* __restrict__ dexp, const float* __restrict__ logits,
                        const int* __restrict__ target,
                        const float* __restrict__ w_onnpu, float* __restrict__ out) {
    float nt_s = 0.f;
    for (int r = threadIdx.x; r < NROWS; r += 1024)
        nt_s += __logf(S_row[r] - dexp[r]) - pos[r];
    float v[8];
#pragma unroll
    for (int i = 0; i < 8; ++i) v[i] = 0.f;
    for (int r = threadIdx.x; r < BATCH; r += 1024) {
        float li = logits[r], lj = logits[BATCH + r];
        bool p = (target[r] == 1);
        float si_n = 1.f / (1.f + __expf(li));
        float si_p = 1.f / (1.f + __expf(-li));
        float sj_n = 1.f / (1.f + __expf(lj));
        float sj_p = 1.f / (1.f + __expf(-lj));
        v[0] += p ? 1.f : 0.f;
        v[1] += p ? 0.f : 1.f;
        v[2] += p ? si_n : 0.f;
        v[3] += p ? si_p : 0.f;
        v[4] += p ? 0.f : si_p;
        v[5] += p ? sj_n : 0.f;
        v[6] += p ? sj_p : 0.f;
        v[7] += p ? 0.f : sj_p;
    }
    __shared__ float red[16][9];
    int wave = threadIdx.x >> 6, lane = threadIdx.x & 63;
    nt_s = wave_reduce_sum(nt_s);
#pragma unroll
    for (int i = 0; i < 8; ++i) v[i] = wave_reduce_sum(v[i]);
    if (lane == 0) {
        red[wave][0] = nt_s;
#pragma unroll
        for (int i = 0; i < 8; ++i) red[wave][1 + i] = v[i];
    }
    __syncthreads();
    if (threadIdx.x == 0) {
        float t[9];
#pragma unroll
        for (int i = 0; i < 9; ++i) {
            float acc = 0.f;
#pragma unroll
            for (int wv = 0; wv < 16; ++wv) acc += red[wv][i];
            t[i] = acc;
        }
        float ntxent = t[0] / (float)NROWS;
        float np = fmaxf(1.f, t[1]), nu = fmaxf(1.f, t[2]);
        float pr_i = PRIOR_PRIMEc / np * t[3];
        float nr_i = (1.f - PRIOR_PRIMEc) / (nu * (1.f - PRIORc)) * t[5]
                   - (1.f - PRIOR_PRIMEc) * PRIORc / (np * (1.f - PRIORc)) * t[4];
        float li_loss = (nr_i < 0.f) ? -nr_i : (pr_i + nr_i);
        float pr_j = PRIOR_PRIMEc / np * t[6];
        float nr_j = (1.f - PRIOR_PRIMEc) / (nu * (1.f - PRIORc)) * t[8]
                   - (1.f - PRIOR_PRIMEc) * PRIORc / (np * (1.f - PRIORc)) * t[7];
        float lj_loss = (nr_j < 0.f) ? -nr_j : (pr_j + nr_j);
        float onnpu = 0.5f * (li_loss + lj_loss);
        float w = w_onnpu[0];
        out[0] = w * onnpu + (1.f - w) * ntxent;
    }
}

extern "C" void kernel_launch(void* const* d_in, const int* in_sizes, int n_in,
                              void* d_out, int out_size, void* d_ws, size_t ws_size,
                              hipStream_t stream) {
    const float* h_i = (const float*)d_in[0];
    const float* h_j = (const float*)d_in[1];
    const float* z_i = (const float*)d_in[2];
    const float* z_j = (const float*)d_in[3];
    const int* target = (const int*)d_in[4];
    const float* W = (const float*)d_in[5];
    const float* b = (const float*)d_in[6];
    const float* w_onnpu = (const float*)d_in[7];

    char* ws = (char*)d_ws;
    unsigned short* znb = (unsigned short*)ws;              // 2 MB swizzled bf16
    float* S_row  = (float*)(ws + 2097152);                 // 32 KB
    float* pos    = (float*)(ws + 2097152 + 32768);         // 32 KB
    float* logits = (float*)(ws + 2097152 + 65536);         // 32 KB
    float* dexp   = (float*)(ws + 2097152 + 98304);         // 32 KB
    float* out = (float*)d_out;

    k_prep<<<3072, 256, 0, stream>>>(z_i, z_j, h_i, h_j, W, b, znb, pos, dexp, S_row, logits);
    k_sim<<<1024, 256, 0, stream>>>(znb, S_row);
    k_final<<<1, 1024, 0, stream>>>(S_row, pos, dexp, logits, target, w_onnpu, out);
}

// Round 3
// 147.579 us; speedup vs baseline: 1.4178x; 1.4178x over previous
//
#include <hip/hip_runtime.h>

#define BATCH  4096
#define NROWS  8192
#define LATENT 2048
#define ZDIM   128
#define PRIORc       0.3f
#define PRIOR_PRIMEc 0.5f

typedef __attribute__((ext_vector_type(8))) short bf16x8;  // 8 bf16 = 4 VGPRs
typedef __attribute__((ext_vector_type(4))) float f32x4;   // MFMA C/D

__device__ inline unsigned short f2bf_rne(float f) {
    unsigned int u = __float_as_uint(f);
    u = u + 0x7fffu + ((u >> 16) & 1u);
    return (unsigned short)(u >> 16);
}

__device__ inline float wave_reduce_sum(float v) {
#pragma unroll
    for (int m = 1; m < 64; m <<= 1) v += __shfl_xor(v, m, 64);
    return v;
}

// ZSCALE = sqrt(2 * log2(e)). Folds BOTH 1/TEMP and the exp->exp2 base change
// into the bf16 fragments: MFMA then yields sim*log2(e), so the sim epilogue
// is a single native v_exp_f32 (exp2) per element.
#define ZSCALE 1.69864464f

// ---------------------------------------------------------------------------
// Prep kernel: fuses the two HBM-independent streams so they share the wire.
//   bids [0,1024):    zprep — normalize, scale by ZSCALE, cast bf16, store
//                     MFMA-swizzled; exact fp32 positive logit; exact bf16
//                     diagonal dexp; zero S_row (folds the memset dispatch).
//   bids [1024,3072): logit GEMV — h_i/h_j @ W^T + b, one wave per row.
// ---------------------------------------------------------------------------
__global__ void k_prep(const float* __restrict__ z_i, const float* __restrict__ z_j,
                       const float* __restrict__ h_i, const float* __restrict__ h_j,
                       const float* __restrict__ W, const float* __restrict__ bb,
                       unsigned short* __restrict__ znb, float* __restrict__ pos,
                       float* __restrict__ dexp, float* __restrict__ S_row,
                       float* __restrict__ logits) {
    int bid = blockIdx.x;
    int wave = threadIdx.x >> 6, lane = threadIdx.x & 63;
    if (bid < 1024) {
        if (threadIdx.x < 8) S_row[bid * 8 + threadIdx.x] = 0.f;
        int r = bid * 4 + wave;               // 0..4095
        int p = r + BATCH;
        float2 a = ((const float2*)(z_i + (size_t)r * ZDIM))[lane];
        float2 c = ((const float2*)(z_j + (size_t)r * ZDIM))[lane];
        float sa = wave_reduce_sum(a.x * a.x + a.y * a.y);
        float sc = wave_reduce_sum(c.x * c.x + c.y * c.y);
        float dd = wave_reduce_sum(a.x * c.x + a.y * c.y);
        float inva = 1.f / fmaxf(sqrtf(sa), 1e-8f);
        float invc = 1.f / fmaxf(sqrtf(sc), 1e-8f);
        if (lane == 0) {
            float pv = 2.0f * dd * inva * invc;   // cos-sim / TEMP, exact fp32
            pos[r] = pv;
            pos[p] = pv;
        }
        int kt = lane >> 4;
        int q  = (lane >> 2) & 3;
        int j  = (lane & 3) * 2;
        int lrow = q * 16;
        float fa = inva * ZSCALE, fc = invc * ZSCALE;
        ushort2 wa; wa.x = f2bf_rne(a.x * fa); wa.y = f2bf_rne(a.y * fa);
        ushort2 wc; wc.x = f2bf_rne(c.x * fc); wc.y = f2bf_rne(c.y * fc);
        {   // row r (from z_i)
            size_t off = ((size_t)((r >> 4) * 4 + kt) * 64 + (lrow + (r & 15))) * 8 + j;
            *(ushort2*)(znb + off) = wa;
        }
        {   // row p (from z_j)
            size_t off = ((size_t)((p >> 4) * 4 + kt) * 64 + (lrow + (p & 15))) * 8 + j;
            *(ushort2*)(znb + off) = wc;
        }
        // diagonal of the bf16 sim matrix, fp32-accumulated like MFMA does
        float ax = __uint_as_float((unsigned)wa.x << 16);
        float ay = __uint_as_float((unsigned)wa.y << 16);
        float cx = __uint_as_float((unsigned)wc.x << 16);
        float cy = __uint_as_float((unsigned)wc.y << 16);
        float da = wave_reduce_sum(ax * ax + ay * ay);
        float dc = wave_reduce_sum(cx * cx + cy * cy);
        if (lane == 0) {
            dexp[r] = __builtin_amdgcn_exp2f(da);
            dexp[p] = __builtin_amdgcn_exp2f(dc);
        }
    } else {
        int r = (bid - 1024) * 4 + wave;      // 0..8191
        const float* h = (r < BATCH) ? (h_i + (size_t)r * LATENT)
                                     : (h_j + (size_t)(r - BATCH) * LATENT);
        const f32x4* h4 = (const f32x4*)h;
        const f32x4* w4 = (const f32x4*)W;
        float s = 0.f;
#pragma unroll
        for (int itr = 0; itr < 8; ++itr) {
            f32x4 av = h4[itr * 64 + lane];
            f32x4 wv = w4[itr * 64 + lane];
            s += av.x * wv.x + av.y * wv.y + av.z * wv.z + av.w * wv.w;
        }
        s = wave_reduce_sum(s);
        if (lane == 0) logits[r] = s + bb[0];
    }
}

// ---------------------------------------------------------------------------
// Sim kernel, PURE. __launch_bounds__(256,3): 3 waves/EU -> unified VGPR cap
// ~170, the proven spill-free codegen point for this body (R1: 84 arch VGPR +
// AGPRs, FETCH ~ znb only). (256,4) capped at 128 and spilled the fragment
// arrays to scratch: R2 showed FETCH 178MB / WRITE 185MB / 95us — 5x loss for
// a 1.33x occupancy bid. Do not raise the bound again.
// 128-row stripe x 512-col group per block; A frags register-resident; B
// frags software-pipelined; per-element epilogue is ONE v_exp (exp2, log2e
// folded into fragments) + ONE v_add (diagonal handled via dexp in k_final).
// ---------------------------------------------------------------------------
__global__ void __launch_bounds__(256, 3) k_sim(
        const unsigned short* __restrict__ znb, float* __restrict__ S_row) {
    int sid = blockIdx.x;
    int lane = threadIdx.x & 63, wave = threadIdx.x >> 6;
    int q = lane >> 4, t = lane & 15;
    int row0 = (sid & 63) * 128 + (wave >> 1) * 64;
    int gA = row0 >> 4;
    const bf16x8* zf = (const bf16x8*)znb;

    bf16x8 a[4][4];
#pragma unroll
    for (int mt = 0; mt < 4; ++mt)
#pragma unroll
        for (int kt = 0; kt < 4; ++kt)
            a[mt][kt] = zf[(size_t)((gA + mt) * 4 + kt) * 64 + lane];

    float s[16];
#pragma unroll
    for (int i = 0; i < 16; ++i) s[i] = 0.f;

    int colbase = (sid >> 6) * 512 + (wave & 1) * 64;
    int cb4 = colbase >> 4;
    bf16x8 b[4];
#pragma unroll
    for (int kt = 0; kt < 4; ++kt)
        b[kt] = zf[(size_t)(cb4 * 4 + kt) * 64 + lane];

#pragma unroll 1
    for (int it = 0; it < 4; ++it) {
#pragma unroll
        for (int nt = 0; nt < 4; ++nt) {
            // prefetch next B fragment group
            bf16x8 bn[4];
            if (!(it == 3 && nt == 3)) {
                int ng = cb4 + (nt == 3 ? (it + 1) * 8 : it * 8 + nt + 1);
#pragma unroll
                for (int kt = 0; kt < 4; ++kt)
                    bn[kt] = zf[(size_t)(ng * 4 + kt) * 64 + lane];
            }
            f32x4 acc[4];
            f32x4 zero = {0.f, 0.f, 0.f, 0.f};
#pragma unroll
            for (int mt = 0; mt < 4; ++mt) acc[mt] = zero;
#pragma unroll
            for (int kt = 0; kt < 4; ++kt)
#pragma unroll
                for (int mt = 0; mt < 4; ++mt)
                    acc[mt] = __builtin_amdgcn_mfma_f32_16x16x32_bf16(a[mt][kt], b[kt], acc[mt], 0, 0, 0);
#pragma unroll
            for (int mt = 0; mt < 4; ++mt)
#pragma unroll
                for (int reg = 0; reg < 4; ++reg)
                    s[mt * 4 + reg] += __builtin_amdgcn_exp2f(acc[mt][reg]);
#pragma unroll
            for (int kt = 0; kt < 4; ++kt) b[kt] = bn[kt];
        }
    }
#pragma unroll
    for (int i = 0; i < 16; ++i) {
        float v = s[i];
        v += __shfl_xor(v, 1, 64);
        v += __shfl_xor(v, 2, 64);
        v += __shfl_xor(v, 4, 64);
        v += __shfl_xor(v, 8, 64);
        if (t == 0) atomicAdd(&S_row[row0 + (i >> 2) * 16 + q * 4 + (i & 3)], v);
    }
}

// Single block: nnPU risk from logits+target, NT-Xent sum from
// S_row (minus exact diagonal dexp) + pos, weighted combine.
__global__ void k_final(const float* __restrict__ S_row, const float* __restrict__ pos,
                        const float* __restrict__ dexp, const float* __restrict__ logits,
                        const int* __restrict__ target,
                        const float* __restrict__ w_onnpu, float* __restrict__ out) {
    float nt_s = 0.f;
    for (int r = threadIdx.x; r < NROWS; r += 1024)
        nt_s += __logf(S_row[r] - dexp[r]) - pos[r];
    float v[8];
#pragma unroll
    for (int i = 0; i < 8; ++i) v[i] = 0.f;
    for (int r = threadIdx.x; r < BATCH; r += 1024) {
        float li = logits[r], lj = logits[BATCH + r];
        bool p = (target[r] == 1);
        float si_n = 1.f / (1.f + __expf(li));
        float si_p = 1.f / (1.f + __expf(-li));
        float sj_n = 1.f / (1.f + __expf(lj));
        float sj_p = 1.f / (1.f + __expf(-lj));
        v[0] += p ? 1.f : 0.f;
        v[1] += p ? 0.f : 1.f;
        v[2] += p ? si_n : 0.f;
        v[3] += p ? si_p : 0.f;
        v[4] += p ? 0.f : si_p;
        v[5] += p ? sj_n : 0.f;
        v[6] += p ? sj_p : 0.f;
        v[7] += p ? 0.f : sj_p;
    }
    __shared__ float red[16][9];
    int wave = threadIdx.x >> 6, lane = threadIdx.x & 63;
    nt_s = wave_reduce_sum(nt_s);
#pragma unroll
    for (int i = 0; i < 8; ++i) v[i] = wave_reduce_sum(v[i]);
    if (lane == 0) {
        red[wave][0] = nt_s;
#pragma unroll
        for (int i = 0; i < 8; ++i) red[wave][1 + i] = v[i];
    }
    __syncthreads();
    if (threadIdx.x == 0) {
        float t[9];
#pragma unroll
        for (int i = 0; i < 9; ++i) {
            float acc = 0.f;
#pragma unroll
            for (int wv = 0; wv < 16; ++wv) acc += red[wv][i];
            t[i] = acc;
        }
        float ntxent = t[0] / (float)NROWS;
        float np = fmaxf(1.f, t[1]), nu = fmaxf(1.f, t[2]);
        float pr_i = PRIOR_PRIMEc / np * t[3];
        float nr_i = (1.f - PRIOR_PRIMEc) / (nu * (1.f - PRIORc)) * t[5]
                   - (1.f - PRIOR_PRIMEc) * PRIORc / (np * (1.f - PRIORc)) * t[4];
        float li_loss = (nr_i < 0.f) ? -nr_i : (pr_i + nr_i);
        float pr_j = PRIOR_PRIMEc / np * t[6];
        float nr_j = (1.f - PRIOR_PRIMEc) / (nu * (1.f - PRIORc)) * t[8]
                   - (1.f - PRIOR_PRIMEc) * PRIORc / (np * (1.f - PRIORc)) * t[7];
        float lj_loss = (nr_j < 0.f) ? -nr_j : (pr_j + nr_j);
        float onnpu = 0.5f * (li_loss + lj_loss);
        float w = w_onnpu[0];
        out[0] = w * onnpu + (1.f - w) * ntxent;
    }
}

extern "C" void kernel_launch(void* const* d_in, const int* in_sizes, int n_in,
                              void* d_out, int out_size, void* d_ws, size_t ws_size,
                              hipStream_t stream) {
    const float* h_i = (const float*)d_in[0];
    const float* h_j = (const float*)d_in[1];
    const float* z_i = (const float*)d_in[2];
    const float* z_j = (const float*)d_in[3];
    const int* target = (const int*)d_in[4];
    const float* W = (const float*)d_in[5];
    const float* b = (const float*)d_in[6];
    const float* w_onnpu = (const float*)d_in[7];

    char* ws = (char*)d_ws;
    unsigned short* znb = (unsigned short*)ws;              // 2 MB swizzled bf16
    float* S_row  = (float*)(ws + 2097152);                 // 32 KB
    float* pos    = (float*)(ws + 2097152 + 32768);         // 32 KB
    float* logits = (float*)(ws + 2097152 + 65536);         // 32 KB
    float* dexp   = (float*)(ws + 2097152 + 98304);         // 32 KB
    float* out = (float*)d_out;

    k_prep<<<3072, 256, 0, stream>>>(z_i, z_j, h_i, h_j, W, b, znb, pos, dexp, S_row, logits);
    k_sim<<<1024, 256, 0, stream>>>(znb, S_row);
    k_final<<<1, 1024, 0, stream>>>(S_row, pos, dexp, logits, target, w_onnpu, out);
}

// Round 4
// 137.052 us; speedup vs baseline: 1.5267x; 1.0768x over previous
//
#include <hip/hip_runtime.h>

#define BATCH  4096
#define NROWS  8192
#define LATENT 2048
#define ZDIM   128
#define PRIORc       0.3f
#define PRIOR_PRIMEc 0.5f

typedef __attribute__((ext_vector_type(8))) short bf16x8;  // 8 bf16 = 4 VGPRs
typedef __attribute__((ext_vector_type(4))) float f32x4;   // MFMA C/D

__device__ inline unsigned short f2bf_rne(float f) {
    unsigned int u = __float_as_uint(f);
    u = u + 0x7fffu + ((u >> 16) & 1u);
    return (unsigned short)(u >> 16);
}

__device__ inline float wave_reduce_sum(float v) {
#pragma unroll
    for (int m = 1; m < 64; m <<= 1) v += __shfl_xor(v, m, 64);
    return v;
}

// ZSCALE = sqrt(2 * log2(e)). Folds BOTH 1/TEMP and the exp->exp2 base change
// into the bf16 fragments: MFMA then yields sim*log2(e), so the sim epilogue
// is a single native v_exp_f32 (exp2) per element.
#define ZSCALE 1.69864464f

// ---------------------------------------------------------------------------
// Prep kernel: fuses the two HBM-independent streams so they share the wire.
//   bids [0,1024):    zprep — normalize, scale by ZSCALE, cast bf16, store
//                     MFMA-swizzled; exact fp32 positive logit; exact bf16
//                     diagonal dexp; zero S_row (folds the memset dispatch).
//   bids [1024,3072): logit GEMV — h_i/h_j @ W^T + b, one wave per row.
// ---------------------------------------------------------------------------
__global__ void k_prep(const float* __restrict__ z_i, const float* __restrict__ z_j,
                       const float* __restrict__ h_i, const float* __restrict__ h_j,
                       const float* __restrict__ W, const float* __restrict__ bb,
                       unsigned short* __restrict__ znb, float* __restrict__ pos,
                       float* __restrict__ dexp, float* __restrict__ S_row,
                       float* __restrict__ logits) {
    int bid = blockIdx.x;
    int wave = threadIdx.x >> 6, lane = threadIdx.x & 63;
    if (bid < 1024) {
        if (threadIdx.x < 8) S_row[bid * 8 + threadIdx.x] = 0.f;
        int r = bid * 4 + wave;               // 0..4095
        int p = r + BATCH;
        float2 a = ((const float2*)(z_i + (size_t)r * ZDIM))[lane];
        float2 c = ((const float2*)(z_j + (size_t)r * ZDIM))[lane];
        float sa = wave_reduce_sum(a.x * a.x + a.y * a.y);
        float sc = wave_reduce_sum(c.x * c.x + c.y * c.y);
        float dd = wave_reduce_sum(a.x * c.x + a.y * c.y);
        float inva = 1.f / fmaxf(sqrtf(sa), 1e-8f);
        float invc = 1.f / fmaxf(sqrtf(sc), 1e-8f);
        if (lane == 0) {
            float pv = 2.0f * dd * inva * invc;   // cos-sim / TEMP, exact fp32
            pos[r] = pv;
            pos[p] = pv;
        }
        int kt = lane >> 4;
        int q  = (lane >> 2) & 3;
        int j  = (lane & 3) * 2;
        int lrow = q * 16;
        float fa = inva * ZSCALE, fc = invc * ZSCALE;
        ushort2 wa; wa.x = f2bf_rne(a.x * fa); wa.y = f2bf_rne(a.y * fa);
        ushort2 wc; wc.x = f2bf_rne(c.x * fc); wc.y = f2bf_rne(c.y * fc);
        {   // row r (from z_i)
            size_t off = ((size_t)((r >> 4) * 4 + kt) * 64 + (lrow + (r & 15))) * 8 + j;
            *(ushort2*)(znb + off) = wa;
        }
        {   // row p (from z_j)
            size_t off = ((size_t)((p >> 4) * 4 + kt) * 64 + (lrow + (p & 15))) * 8 + j;
            *(ushort2*)(znb + off) = wc;
        }
        // diagonal of the bf16 sim matrix, fp32-accumulated like MFMA does
        float ax = __uint_as_float((unsigned)wa.x << 16);
        float ay = __uint_as_float((unsigned)wa.y << 16);
        float cx = __uint_as_float((unsigned)wc.x << 16);
        float cy = __uint_as_float((unsigned)wc.y << 16);
        float da = wave_reduce_sum(ax * ax + ay * ay);
        float dc = wave_reduce_sum(cx * cx + cy * cy);
        if (lane == 0) {
            dexp[r] = __builtin_amdgcn_exp2f(da);
            dexp[p] = __builtin_amdgcn_exp2f(dc);
        }
    } else {
        int r = (bid - 1024) * 4 + wave;      // 0..8191
        const float* h = (r < BATCH) ? (h_i + (size_t)r * LATENT)
                                     : (h_j + (size_t)(r - BATCH) * LATENT);
        const f32x4* h4 = (const f32x4*)h;
        const f32x4* w4 = (const f32x4*)W;
        float s = 0.f;
#pragma unroll
        for (int itr = 0; itr < 8; ++itr) {
            f32x4 av = h4[itr * 64 + lane];
            f32x4 wv = w4[itr * 64 + lane];
            s += av.x * wv.x + av.y * wv.y + av.z * wv.z + av.w * wv.w;
        }
        s = wave_reduce_sum(s);
        if (lane == 0) logits[r] = s + bb[0];
    }
}

// ---------------------------------------------------------------------------
// Sim kernel, SYMMETRIC-HALF: the sim matrix S = f(Z Z^T) is symmetric, and
// with both MFMA operands read from the same swizzled znb the (i,j) and
// (j,i) tiles are BITWISE equal (same bf16 products, same hardware k-order).
// So compute only upper-triangle 128x128 tiles (2080 blocks = 64*65/2) and
// accumulate BOTH row-sums and col-sums of each off-diagonal tile: halves
// MFMA+exp work AND fragment traffic vs R3, doubles block parallelism, and
// cuts the per-block serial prefetch chain 16 -> 4 iterations (R3's k_sim ran
// at ~13% MfmaUtil = 85% latency stall).
// Col-sums are near-free from the C-fragment layout: per nt, each lane's 16
// exps share one column -> 1 per-lane partial + shfl_xor(16,32).
// Per-block LDS staging (256 floats) keeps global atomics to 1/row + 1/col.
// __launch_bounds__(256,3): proven spill-free envelope (R2: (256,4) spilled
// fragment arrays to scratch, 5x loss — do not raise).
// ---------------------------------------------------------------------------
__global__ void __launch_bounds__(256, 3) k_sim(
        const unsigned short* __restrict__ znb, float* __restrict__ S_row) {
    int k = blockIdx.x;                       // 0..2079 upper-tri tile id
    // map k -> (i,j), i<=j, 64 stripes: T(i) = i*(129-i)/2 tiles before row i
    int i = (int)((129.0f - sqrtf(16641.0f - 8.0f * (float)k)) * 0.5f);
    if (i > 63) i = 63;
    while (i * (129 - i) / 2 > k) --i;
    while ((i + 1) * (128 - i) / 2 <= k) ++i;
    int j = i + (k - i * (129 - i) / 2);
    bool diag = (i == j);

    int lane = threadIdx.x & 63, wave = threadIdx.x >> 6;
    int q = lane >> 4, t = lane & 15;
    int row0 = i * 128 + (wave >> 1) * 64;
    int colbase = j * 128 + (wave & 1) * 64;
    int gA = row0 >> 4;
    int cb4 = colbase >> 4;
    const bf16x8* zf = (const bf16x8*)znb;

    __shared__ float red[256];                // [0,128) rows, [128,256) cols
    red[threadIdx.x] = 0.f;
    __syncthreads();

    bf16x8 a[4][4];
#pragma unroll
    for (int mt = 0; mt < 4; ++mt)
#pragma unroll
        for (int kt = 0; kt < 4; ++kt)
            a[mt][kt] = zf[(size_t)((gA + mt) * 4 + kt) * 64 + lane];

    bf16x8 b[4];
#pragma unroll
    for (int kt = 0; kt < 4; ++kt)
        b[kt] = zf[(size_t)(cb4 * 4 + kt) * 64 + lane];

    float s[16];
#pragma unroll
    for (int idx = 0; idx < 16; ++idx) s[idx] = 0.f;
    float c[4];

#pragma unroll
    for (int nt = 0; nt < 4; ++nt) {
        bf16x8 bn[4];
        if (nt < 3) {
#pragma unroll
            for (int kt = 0; kt < 4; ++kt)
                bn[kt] = zf[(size_t)((cb4 + nt + 1) * 4 + kt) * 64 + lane];
        }
        f32x4 acc[4];
        f32x4 zero = {0.f, 0.f, 0.f, 0.f};
#pragma unroll
        for (int mt = 0; mt < 4; ++mt) acc[mt] = zero;
#pragma unroll
        for (int kt = 0; kt < 4; ++kt)
#pragma unroll
            for (int mt = 0; mt < 4; ++mt)
                acc[mt] = __builtin_amdgcn_mfma_f32_16x16x32_bf16(a[mt][kt], b[kt], acc[mt], 0, 0, 0);
        float csum = 0.f;
#pragma unroll
        for (int mt = 0; mt < 4; ++mt)
#pragma unroll
            for (int reg = 0; reg < 4; ++reg) {
                float e = __builtin_amdgcn_exp2f(acc[mt][reg]);
                s[mt * 4 + reg] += e;
                csum += e;
            }
        c[nt] = csum;
        if (nt < 3) {
#pragma unroll
            for (int kt = 0; kt < 4; ++kt) b[kt] = bn[kt];
        }
    }

    // row sums: reduce over t (16 lanes within q-group) -> LDS
#pragma unroll
    for (int idx = 0; idx < 16; ++idx) {
        float v = s[idx];
        v += __shfl_xor(v, 1, 64);
        v += __shfl_xor(v, 2, 64);
        v += __shfl_xor(v, 4, 64);
        v += __shfl_xor(v, 8, 64);
        if (t == 0)
            atomicAdd(&red[(wave >> 1) * 64 + (idx >> 2) * 16 + q * 4 + (idx & 3)], v);
    }
    // col sums: reduce over q (xor 16,32) -> LDS
#pragma unroll
    for (int nt = 0; nt < 4; ++nt) {
        float v = c[nt];
        v += __shfl_xor(v, 16, 64);
        v += __shfl_xor(v, 32, 64);
        if (q == 0)
            atomicAdd(&red[128 + (wave & 1) * 64 + nt * 16 + t], v);
    }
    __syncthreads();
    if (threadIdx.x < 128) {
        atomicAdd(&S_row[i * 128 + threadIdx.x], red[threadIdx.x]);
    } else if (!diag) {
        atomicAdd(&S_row[j * 128 + (threadIdx.x & 127)], red[threadIdx.x]);
    }
}

// Single block: nnPU risk from logits+target, NT-Xent sum from
// S_row (minus exact diagonal dexp) + pos, weighted combine.
__global__ void k_final(const float* __restrict__ S_row, const float* __restrict__ pos,
                        const float* __restrict__ dexp, const float* __restrict__ logits,
                        const int* __restrict__ target,
                        const float* __restrict__ w_onnpu, float* __restrict__ out) {
    float nt_s = 0.f;
    for (int r = threadIdx.x; r < NROWS; r += 1024)
        nt_s += __logf(S_row[r] - dexp[r]) - pos[r];
    float v[8];
#pragma unroll
    for (int i = 0; i < 8; ++i) v[i] = 0.f;
    for (int r = threadIdx.x; r < BATCH; r += 1024) {
        float li = logits[r], lj = logits[BATCH + r];
        bool p = (target[r] == 1);
        float si_n = 1.f / (1.f + __expf(li));
        float si_p = 1.f / (1.f + __expf(-li));
        float sj_n = 1.f / (1.f + __expf(lj));
        float sj_p = 1.f / (1.f + __expf(-lj));
        v[0] += p ? 1.f : 0.f;
        v[1] += p ? 0.f : 1.f;
        v[2] += p ? si_n : 0.f;
        v[3] += p ? si_p : 0.f;
        v[4] += p ? 0.f : si_p;
        v[5] += p ? sj_n : 0.f;
        v[6] += p ? sj_p : 0.f;
        v[7] += p ? 0.f : sj_p;
    }
    __shared__ float red[16][9];
    int wave = threadIdx.x >> 6, lane = threadIdx.x & 63;
    nt_s = wave_reduce_sum(nt_s);
#pragma unroll
    for (int i = 0; i < 8; ++i) v[i] = wave_reduce_sum(v[i]);
    if (lane == 0) {
        red[wave][0] = nt_s;
#pragma unroll
        for (int i = 0; i < 8; ++i) red[wave][1 + i] = v[i];
    }
    __syncthreads();
    if (threadIdx.x == 0) {
        float t[9];
#pragma unroll
        for (int i = 0; i < 9; ++i) {
            float acc = 0.f;
#pragma unroll
            for (int wv = 0; wv < 16; ++wv) acc += red[wv][i];
            t[i] = acc;
        }
        float ntxent = t[0] / (float)NROWS;
        float np = fmaxf(1.f, t[1]), nu = fmaxf(1.f, t[2]);
        float pr_i = PRIOR_PRIMEc / np * t[3];
        float nr_i = (1.f - PRIOR_PRIMEc) / (nu * (1.f - PRIORc)) * t[5]
                   - (1.f - PRIOR_PRIMEc) * PRIORc / (np * (1.f - PRIORc)) * t[4];
        float li_loss = (nr_i < 0.f) ? -nr_i : (pr_i + nr_i);
        float pr_j = PRIOR_PRIMEc / np * t[6];
        float nr_j = (1.f - PRIOR_PRIMEc) / (nu * (1.f - PRIORc)) * t[8]
                   - (1.f - PRIOR_PRIMEc) * PRIORc / (np * (1.f - PRIORc)) * t[7];
        float lj_loss = (nr_j < 0.f) ? -nr_j : (pr_j + nr_j);
        float onnpu = 0.5f * (li_loss + lj_loss);
        float w = w_onnpu[0];
        out[0] = w * onnpu + (1.f - w) * ntxent;
    }
}

extern "C" void kernel_launch(void* const* d_in, const int* in_sizes, int n_in,
                              void* d_out, int out_size, void* d_ws, size_t ws_size,
                              hipStream_t stream) {
    const float* h_i = (const float*)d_in[0];
    const float* h_j = (const float*)d_in[1];
    const float* z_i = (const float*)d_in[2];
    const float* z_j = (const float*)d_in[3];
    const int* target = (const int*)d_in[4];
    const float* W = (const float*)d_in[5];
    const float* b = (const float*)d_in[6];
    const float* w_onnpu = (const float*)d_in[7];

    char* ws = (char*)d_ws;
    unsigned short* znb = (unsigned short*)ws;              // 2 MB swizzled bf16
    float* S_row  = (float*)(ws + 2097152);                 // 32 KB
    float* pos    = (float*)(ws + 2097152 + 32768);         // 32 KB
    float* logits = (float*)(ws + 2097152 + 65536);         // 32 KB
    float* dexp   = (float*)(ws + 2097152 + 98304);         // 32 KB
    float* out = (float*)d_out;

    k_prep<<<3072, 256, 0, stream>>>(z_i, z_j, h_i, h_j, W, b, znb, pos, dexp, S_row, logits);
    k_sim<<<2080, 256, 0, stream>>>(znb, S_row);
    k_final<<<1, 1024, 0, stream>>>(S_row, pos, dexp, logits, target, w_onnpu, out);
}

// Round 6
// 133.600 us; speedup vs baseline: 1.5662x; 1.0258x over previous
//
#include <hip/hip_runtime.h>

#define BATCH  4096
#define NROWS  8192
#define LATENT 2048
#define ZDIM   128
#define PRIORc       0.3f
#define PRIOR_PRIMEc 0.5f

#define NSIM 2080   // 64*65/2 upper-triangle 128x128 tiles

typedef __attribute__((ext_vector_type(8))) short bf16x8;  // 8 bf16 = 4 VGPRs
typedef __attribute__((ext_vector_type(4))) float f32x4;   // MFMA C/D

__device__ inline unsigned short f2bf_rne(float f) {
    unsigned int u = __float_as_uint(f);
    u = u + 0x7fffu + ((u >> 16) & 1u);
    return (unsigned short)(u >> 16);
}

__device__ inline float wave_reduce_sum(float v) {
#pragma unroll
    for (int m = 1; m < 64; m <<= 1) v += __shfl_xor(v, m, 64);
    return v;
}

// ZSCALE = sqrt(2 * log2(e)). Folds BOTH 1/TEMP and the exp->exp2 base change
// into the bf16 fragments: MFMA then yields sim*log2(e), so the sim epilogue
// is a single native v_exp_f32 (exp2) per element.
#define ZSCALE 1.69864464f

// ---------------------------------------------------------------------------
// zprep ONLY (the 64MB logit GEMV moved to k_main where it overlaps sim's
// latency-stall tail instead of running serially before it): normalize, scale
// by ZSCALE, cast bf16, store MFMA-swizzled; exact fp32 positive logit; exact
// bf16 diagonal dexp; zero S_row. ~6MB of traffic -> ~2us.
// ---------------------------------------------------------------------------
__global__ void k_zprep(const float* __restrict__ z_i, const float* __restrict__ z_j,
                        unsigned short* __restrict__ znb, float* __restrict__ pos,
                        float* __restrict__ dexp, float* __restrict__ S_row) {
    int bid = blockIdx.x;
    int wave = threadIdx.x >> 6, lane = threadIdx.x & 63;
    if (threadIdx.x < 8) S_row[bid * 8 + threadIdx.x] = 0.f;
    int r = bid * 4 + wave;               // 0..4095
    int p = r + BATCH;
    float2 a = ((const float2*)(z_i + (size_t)r * ZDIM))[lane];
    float2 c = ((const float2*)(z_j + (size_t)r * ZDIM))[lane];
    float sa = wave_reduce_sum(a.x * a.x + a.y * a.y);
    float sc = wave_reduce_sum(c.x * c.x + c.y * c.y);
    float dd = wave_reduce_sum(a.x * c.x + a.y * c.y);
    float inva = 1.f / fmaxf(sqrtf(sa), 1e-8f);
    float invc = 1.f / fmaxf(sqrtf(sc), 1e-8f);
    if (lane == 0) {
        float pv = 2.0f * dd * inva * invc;   // cos-sim / TEMP, exact fp32
        pos[r] = pv;
        pos[p] = pv;
    }
    int kt = lane >> 4;
    int q  = (lane >> 2) & 3;
    int j  = (lane & 3) * 2;
    int lrow = q * 16;
    float fa = inva * ZSCALE, fc = invc * ZSCALE;
    ushort2 wa; wa.x = f2bf_rne(a.x * fa); wa.y = f2bf_rne(a.y * fa);
    ushort2 wc; wc.x = f2bf_rne(c.x * fc); wc.y = f2bf_rne(c.y * fc);
    {   // row r (from z_i)
        size_t off = ((size_t)((r >> 4) * 4 + kt) * 64 + (lrow + (r & 15))) * 8 + j;
        *(ushort2*)(znb + off) = wa;
    }
    {   // row p (from z_j)
        size_t off = ((size_t)((p >> 4) * 4 + kt) * 64 + (lrow + (p & 15))) * 8 + j;
        *(ushort2*)(znb + off) = wc;
    }
    // diagonal of the bf16 sim matrix, fp32-accumulated like MFMA does
    float ax = __uint_as_float((unsigned)wa.x << 16);
    float ay = __uint_as_float((unsigned)wa.y << 16);
    float cx = __uint_as_float((unsigned)wc.x << 16);
    float cy = __uint_as_float((unsigned)wc.y << 16);
    float da = wave_reduce_sum(ax * ax + ay * ay);
    float dc = wave_reduce_sum(cx * cx + cy * cy);
    if (lane == 0) {
        dexp[r] = __builtin_amdgcn_exp2f(da);
        dexp[p] = __builtin_amdgcn_exp2f(dc);
    }
}

// ---------------------------------------------------------------------------
// Main kernel. bids [0,NSIM) = symmetric-half sim tiles; bids [NSIM,NSIM+2048)
// = logit GEMV. ORDERED, not interleaved (R1 lesson): the CP dispatches in
// ascending bid with backfill, so all CUs fill with sim first and GEMV blocks
// launch only as sim blocks retire — the 64MB GEMV stream overlaps sim's
// drain tail (sim is ~85% latency-stall per R3 counters) instead of running
// serially before it (R3/R4 structure).
// Sim body unchanged from R4 (bitwise-symmetric upper-tri tiles, row+col
// sums, LDS staging, dexp diagonal). __launch_bounds__(256,3): proven
// spill-free envelope (R2: (256,4) spilled fragments to scratch, 5x loss).
// ---------------------------------------------------------------------------
__global__ void __launch_bounds__(256, 3) k_main(
        const unsigned short* __restrict__ znb, float* __restrict__ S_row,
        const float* __restrict__ h_i, const float* __restrict__ h_j,
        const float* __restrict__ W, const float* __restrict__ bb,
        float* __restrict__ logits) {
    int bid = blockIdx.x;
    int lane = threadIdx.x & 63, wave = threadIdx.x >> 6;
    if (bid < NSIM) {
        int k = bid;                          // 0..2079 upper-tri tile id
        // map k -> (i,j), i<=j, 64 stripes: T(i) = i*(129-i)/2 tiles before row i
        int i = (int)((129.0f - sqrtf(16641.0f - 8.0f * (float)k)) * 0.5f);
        if (i > 63) i = 63;
        while (i * (129 - i) / 2 > k) --i;
        while ((i + 1) * (128 - i) / 2 <= k) ++i;
        int j = i + (k - i * (129 - i) / 2);
        bool diag = (i == j);

        int q = lane >> 4, t = lane & 15;
        int row0 = i * 128 + (wave >> 1) * 64;
        int colbase = j * 128 + (wave & 1) * 64;
        int gA = row0 >> 4;
        int cb4 = colbase >> 4;
        const bf16x8* zf = (const bf16x8*)znb;

        __shared__ float red[256];            // [0,128) rows, [128,256) cols
        red[threadIdx.x] = 0.f;
        __syncthreads();

        bf16x8 a[4][4];
#pragma unroll
        for (int mt = 0; mt < 4; ++mt)
#pragma unroll
            for (int kt = 0; kt < 4; ++kt)
                a[mt][kt] = zf[(size_t)((gA + mt) * 4 + kt) * 64 + lane];

        bf16x8 b[4];
#pragma unroll
        for (int kt = 0; kt < 4; ++kt)
            b[kt] = zf[(size_t)(cb4 * 4 + kt) * 64 + lane];

        float s[16];
#pragma unroll
        for (int idx = 0; idx < 16; ++idx) s[idx] = 0.f;
        float c[4];

#pragma unroll
        for (int nt = 0; nt < 4; ++nt) {
            bf16x8 bn[4];
            if (nt < 3) {
#pragma unroll
                for (int kt = 0; kt < 4; ++kt)
                    bn[kt] = zf[(size_t)((cb4 + nt + 1) * 4 + kt) * 64 + lane];
            }
            f32x4 acc[4];
            f32x4 zero = {0.f, 0.f, 0.f, 0.f};
#pragma unroll
            for (int mt = 0; mt < 4; ++mt) acc[mt] = zero;
#pragma unroll
            for (int kt = 0; kt < 4; ++kt)
#pragma unroll
                for (int mt = 0; mt < 4; ++mt)
                    acc[mt] = __builtin_amdgcn_mfma_f32_16x16x32_bf16(a[mt][kt], b[kt], acc[mt], 0, 0, 0);
            float csum = 0.f;
#pragma unroll
            for (int mt = 0; mt < 4; ++mt)
#pragma unroll
                for (int reg = 0; reg < 4; ++reg) {
                    float e = __builtin_amdgcn_exp2f(acc[mt][reg]);
                    s[mt * 4 + reg] += e;
                    csum += e;
                }
            c[nt] = csum;
            if (nt < 3) {
#pragma unroll
                for (int kt = 0; kt < 4; ++kt) b[kt] = bn[kt];
            }
        }

        // row sums: reduce over t (16 lanes within q-group) -> LDS
#pragma unroll
        for (int idx = 0; idx < 16; ++idx) {
            float v = s[idx];
            v += __shfl_xor(v, 1, 64);
            v += __shfl_xor(v, 2, 64);
            v += __shfl_xor(v, 4, 64);
            v += __shfl_xor(v, 8, 64);
            if (t == 0)
                atomicAdd(&red[(wave >> 1) * 64 + (idx >> 2) * 16 + q * 4 + (idx & 3)], v);
        }
        // col sums: reduce over q (xor 16,32) -> LDS
#pragma unroll
        for (int nt = 0; nt < 4; ++nt) {
            float v = c[nt];
            v += __shfl_xor(v, 16, 64);
            v += __shfl_xor(v, 32, 64);
            if (q == 0)
                atomicAdd(&red[128 + (wave & 1) * 64 + nt * 16 + t], v);
        }
        __syncthreads();
        if (threadIdx.x < 128) {
            atomicAdd(&S_row[i * 128 + threadIdx.x], red[threadIdx.x]);
        } else if (!diag) {
            atomicAdd(&S_row[j * 128 + (threadIdx.x & 127)], red[threadIdx.x]);
        }
    } else {
        int r = (bid - NSIM) * 4 + wave;      // 0..8191
        const float* h = (r < BATCH) ? (h_i + (size_t)r * LATENT)
                                     : (h_j + (size_t)(r - BATCH) * LATENT);
        const f32x4* h4 = (const f32x4*)h;
        const f32x4* w4 = (const f32x4*)W;
        float s = 0.f;
#pragma unroll
        for (int itr = 0; itr < 8; ++itr) {
            f32x4 av = h4[itr * 64 + lane];
            f32x4 wv = w4[itr * 64 + lane];
            s += av.x * wv.x + av.y * wv.y + av.z * wv.z + av.w * wv.w;
        }
        s = wave_reduce_sum(s);
        if (lane == 0) logits[r] = s + bb[0];
    }
}

// Single block: nnPU risk from logits+target, NT-Xent sum from
// S_row (minus exact diagonal dexp) + pos, weighted combine.
__global__ void k_final(const float* __restrict__ S_row, const float* __restrict__ pos,
                        const float* __restrict__ dexp, const float* __restrict__ logits,
                        const int* __restrict__ target,
                        const float* __restrict__ w_onnpu, float* __restrict__ out) {
    float nt_s = 0.f;
    for (int r = threadIdx.x; r < NROWS; r += 1024)
        nt_s += __logf(S_row[r] - dexp[r]) - pos[r];
    float v[8];
#pragma unroll
    for (int i = 0; i < 8; ++i) v[i] = 0.f;
    for (int r = threadIdx.x; r < BATCH; r += 1024) {
        float li = logits[r], lj = logits[BATCH + r];
        bool p = (target[r] == 1);
        float si_n = 1.f / (1.f + __expf(li));
        float si_p = 1.f / (1.f + __expf(-li));
        float sj_n = 1.f / (1.f + __expf(lj));
        float sj_p = 1.f / (1.f + __expf(-lj));
        v[0] += p ? 1.f : 0.f;
        v[1] += p ? 0.f : 1.f;
        v[2] += p ? si_n : 0.f;
        v[3] += p ? si_p : 0.f;
        v[4] += p ? 0.f : si_p;
        v[5] += p ? sj_n : 0.f;
        v[6] += p ? sj_p : 0.f;
        v[7] += p ? 0.f : sj_p;
    }
    __shared__ float red[16][9];
    int wave = threadIdx.x >> 6, lane = threadIdx.x & 63;
    nt_s = wave_reduce_sum(nt_s);
#pragma unroll
    for (int i = 0; i < 8; ++i) v[i] = wave_reduce_sum(v[i]);
    if (lane == 0) {
        red[wave][0] = nt_s;
#pragma unroll
        for (int i = 0; i < 8; ++i) red[wave][1 + i] = v[i];
    }
    __syncthreads();
    if (threadIdx.x == 0) {
        float t[9];
#pragma unroll
        for (int i = 0; i < 9; ++i) {
            float acc = 0.f;
#pragma unroll
            for (int wv = 0; wv < 16; ++wv) acc += red[wv][i];
            t[i] = acc;
        }
        float ntxent = t[0] / (float)NROWS;
        float np = fmaxf(1.f, t[1]), nu = fmaxf(1.f, t[2]);
        float pr_i = PRIOR_PRIMEc / np * t[3];
        float nr_i = (1.f - PRIOR_PRIMEc) / (nu * (1.f - PRIORc)) * t[5]
                   - (1.f - PRIOR_PRIMEc) * PRIORc / (np * (1.f - PRIORc)) * t[4];
        float li_loss = (nr_i < 0.f) ? -nr_i : (pr_i + nr_i);
        float pr_j = PRIOR_PRIMEc / np * t[6];
        float nr_j = (1.f - PRIOR_PRIMEc) / (nu * (1.f - PRIORc)) * t[8]
                   - (1.f - PRIOR_PRIMEc) * PRIORc / (np * (1.f - PRIORc)) * t[7];
        float lj_loss = (nr_j < 0.f) ? -nr_j : (pr_j + nr_j);
        float onnpu = 0.5f * (li_loss + lj_loss);
        float w = w_onnpu[0];
        out[0] = w * onnpu + (1.f - w) * ntxent;
    }
}

extern "C" void kernel_launch(void* const* d_in, const int* in_sizes, int n_in,
                              void* d_out, int out_size, void* d_ws, size_t ws_size,
                              hipStream_t stream) {
    const float* h_i = (const float*)d_in[0];
    const float* h_j = (const float*)d_in[1];
    const float* z_i = (const float*)d_in[2];
    const float* z_j = (const float*)d_in[3];
    const int* target = (const int*)d_in[4];
    const float* W = (const float*)d_in[5];
    const float* b = (const float*)d_in[6];
    const float* w_onnpu = (const float*)d_in[7];

    char* ws = (char*)d_ws;
    unsigned short* znb = (unsigned short*)ws;              // 2 MB swizzled bf16
    float* S_row  = (float*)(ws + 2097152);                 // 32 KB
    float* pos    = (float*)(ws + 2097152 + 32768);         // 32 KB
    float* logits = (float*)(ws + 2097152 + 65536);         // 32 KB
    float* dexp   = (float*)(ws + 2097152 + 98304);         // 32 KB
    float* out = (float*)d_out;

    k_zprep<<<1024, 256, 0, stream>>>(z_i, z_j, znb, pos, dexp, S_row);
    k_main<<<NSIM + 2048, 256, 0, stream>>>(znb, S_row, h_i, h_j, W, b, logits);
    k_final<<<1, 1024, 0, stream>>>(S_row, pos, dexp, logits, target, w_onnpu, out);
}

// Round 7
// 133.322 us; speedup vs baseline: 1.5695x; 1.0021x over previous
//
#include <hip/hip_runtime.h>

#define BATCH  4096
#define NROWS  8192
#define LATENT 2048
#define ZDIM   128
#define PRIORc       0.3f
#define PRIOR_PRIMEc 0.5f

#define NSIM 2080   // 64*65/2 upper-triangle 128x128 tiles

typedef __attribute__((ext_vector_type(8))) short bf16x8;  // 8 bf16 = 4 VGPRs
typedef __attribute__((ext_vector_type(4))) float f32x4;   // MFMA C/D

__device__ inline unsigned short f2bf_rne(float f) {
    unsigned int u = __float_as_uint(f);
    u = u + 0x7fffu + ((u >> 16) & 1u);
    return (unsigned short)(u >> 16);
}

__device__ inline float wave_reduce_sum(float v) {
#pragma unroll
    for (int m = 1; m < 64; m <<= 1) v += __shfl_xor(v, m, 64);
    return v;
}

// async global->LDS, 16B per lane (dest = wave-uniform base + lane*16)
__device__ inline void gload_lds16(const void* g, void* l) {
    __builtin_amdgcn_global_load_lds(
        (const __attribute__((address_space(1))) unsigned int*)g,
        (__attribute__((address_space(3))) unsigned int*)l, 16, 0, 0);
}

// ZSCALE = sqrt(2 * log2(e)). Folds BOTH 1/TEMP and the exp->exp2 base change
// into the bf16 fragments: MFMA then yields sim*log2(e), so the sim epilogue
// is a single native v_exp_f32 (exp2) per element.
#define ZSCALE 1.69864464f

// ---------------------------------------------------------------------------
// zprep: normalize, scale by ZSCALE, cast bf16, store MFMA-swizzled; exact
// fp32 positive logit; exact bf16 diagonal dexp; zero S_row.
// ---------------------------------------------------------------------------
__global__ void k_zprep(const float* __restrict__ z_i, const float* __restrict__ z_j,
                        unsigned short* __restrict__ znb, float* __restrict__ pos,
                        float* __restrict__ dexp, float* __restrict__ S_row) {
    int bid = blockIdx.x;
    int wave = threadIdx.x >> 6, lane = threadIdx.x & 63;
    if (threadIdx.x < 8) S_row[bid * 8 + threadIdx.x] = 0.f;
    int r = bid * 4 + wave;               // 0..4095
    int p = r + BATCH;
    float2 a = ((const float2*)(z_i + (size_t)r * ZDIM))[lane];
    float2 c = ((const float2*)(z_j + (size_t)r * ZDIM))[lane];
    float sa = wave_reduce_sum(a.x * a.x + a.y * a.y);
    float sc = wave_reduce_sum(c.x * c.x + c.y * c.y);
    float dd = wave_reduce_sum(a.x * c.x + a.y * c.y);
    float inva = 1.f / fmaxf(sqrtf(sa), 1e-8f);
    float invc = 1.f / fmaxf(sqrtf(sc), 1e-8f);
    if (lane == 0) {
        float pv = 2.0f * dd * inva * invc;   // cos-sim / TEMP, exact fp32
        pos[r] = pv;
        pos[p] = pv;
    }
    int kt = lane >> 4;
    int q  = (lane >> 2) & 3;
    int j  = (lane & 3) * 2;
    int lrow = q * 16;
    float fa = inva * ZSCALE, fc = invc * ZSCALE;
    ushort2 wa; wa.x = f2bf_rne(a.x * fa); wa.y = f2bf_rne(a.y * fa);
    ushort2 wc; wc.x = f2bf_rne(c.x * fc); wc.y = f2bf_rne(c.y * fc);
    {   // row r (from z_i)
        size_t off = ((size_t)((r >> 4) * 4 + kt) * 64 + (lrow + (r & 15))) * 8 + j;
        *(ushort2*)(znb + off) = wa;
    }
    {   // row p (from z_j)
        size_t off = ((size_t)((p >> 4) * 4 + kt) * 64 + (lrow + (p & 15))) * 8 + j;
        *(ushort2*)(znb + off) = wc;
    }
    // diagonal of the bf16 sim matrix, fp32-accumulated like MFMA does
    float ax = __uint_as_float((unsigned)wa.x << 16);
    float ay = __uint_as_float((unsigned)wa.y << 16);
    float cx = __uint_as_float((unsigned)wc.x << 16);
    float cy = __uint_as_float((unsigned)wc.y << 16);
    float da = wave_reduce_sum(ax * ax + ay * ay);
    float dc = wave_reduce_sum(cx * cx + cy * cy);
    if (lane == 0) {
        dexp[r] = __builtin_amdgcn_exp2f(da);
        dexp[p] = __builtin_amdgcn_exp2f(dc);
    }
}

// ---------------------------------------------------------------------------
// Main kernel. bids [0,NSIM) = symmetric-half sim tiles; bids >= NSIM = logit
// GEMV (ordered grid: GEMV backfills as sim retires, overlapping sim's tail).
//
// R6 fix: R6 counters showed VGPR_Count=72 (< the ~130 needed for resident
// fragments) and MfmaUtil 7.4% — the allocator was re-loading fragments from
// global inside the nt loop, putting L2/L3 latency on every iteration. Now
// the B panel (a CONTIGUOUS 32KB span of znb, thanks to the swizzled chunk
// layout) is bulk-staged into LDS via global_load_lds width=16 (linear dest
// = wave-uniform base + lane*16, exactly matching the layout). All B latency
// is paid once per block in bulk; the nt loop reads fragments via conflict-
// free ds_read_b128 and has NO global loads. bn prefetch buffers deleted ->
// 16 fewer VGPRs -> a[4][4] stays resident.
// __launch_bounds__(256,3): proven spill-free envelope (R2: (256,4) spilled,
// 5x loss). LDS 33KB -> 3 blocks/CU fits.
// ---------------------------------------------------------------------------
__global__ void __launch_bounds__(256, 3) k_main(
        const unsigned short* __restrict__ znb, float* __restrict__ S_row,
        const float* __restrict__ h_i, const float* __restrict__ h_j,
        const float* __restrict__ W, const float* __restrict__ bb,
        float* __restrict__ logits) {
    int bid = blockIdx.x;
    int lane = threadIdx.x & 63, wave = threadIdx.x >> 6;
    if (bid < NSIM) {
        int k = bid;                          // 0..2079 upper-tri tile id
        // map k -> (i,j), i<=j: T(i) = i*(129-i)/2 tiles before row i
        int i = (int)((129.0f - sqrtf(16641.0f - 8.0f * (float)k)) * 0.5f);
        if (i > 63) i = 63;
        while (i * (129 - i) / 2 > k) --i;
        while ((i + 1) * (128 - i) / 2 <= k) ++i;
        int j = i + (k - i * (129 - i) / 2);
        bool diag = (i == j);

        int q = lane >> 4, t = lane & 15;
        int row0 = i * 128 + (wave >> 1) * 64;
        int gA = row0 >> 4;

        __shared__ __align__(16) unsigned char bpan[32768];  // B panel j (32KB)
        __shared__ float red[256];            // [0,128) rows, [128,256) cols
        red[threadIdx.x] = 0.f;

        // bulk async stage of B panel: znb[j*32KB .. +32KB) -> bpan, linear.
        // 8 issues x 256 threads x 16B. Per-wave LDS base is uniform; HW adds
        // lane*16.
        {
            const unsigned char* gsrc = (const unsigned char*)znb + (size_t)j * 32768;
#pragma unroll
            for (int u = 0; u < 8; ++u) {
                int boff = u * 4096 + wave * 1024 + lane * 16;
                gload_lds16(gsrc + boff, bpan + u * 4096 + wave * 1024);
            }
        }

        // A fragments -> registers (independent of LDS staging)
        const bf16x8* zf = (const bf16x8*)znb;
        bf16x8 a[4][4];
#pragma unroll
        for (int mt = 0; mt < 4; ++mt)
#pragma unroll
            for (int kt = 0; kt < 4; ++kt)
                a[mt][kt] = zf[(size_t)((gA + mt) * 4 + kt) * 64 + lane];

        float s[16];
#pragma unroll
        for (int idx = 0; idx < 16; ++idx) s[idx] = 0.f;
        float c[4];

        __syncthreads();   // drains vmcnt(0): staging + red-zero both visible

#pragma unroll
        for (int nt = 0; nt < 4; ++nt) {
            // B fragments from LDS: local chunk ((wave&1)*4+nt)*4+kt, 1KB each
            bf16x8 b[4];
#pragma unroll
            for (int kt = 0; kt < 4; ++kt)
                b[kt] = *(const bf16x8*)(bpan +
                        ((size_t)(((wave & 1) * 4 + nt) * 4 + kt) * 1024) + lane * 16);
            f32x4 acc[4];
            f32x4 zero = {0.f, 0.f, 0.f, 0.f};
#pragma unroll
            for (int mt = 0; mt < 4; ++mt) acc[mt] = zero;
#pragma unroll
            for (int kt = 0; kt < 4; ++kt)
#pragma unroll
                for (int mt = 0; mt < 4; ++mt)
                    acc[mt] = __builtin_amdgcn_mfma_f32_16x16x32_bf16(a[mt][kt], b[kt], acc[mt], 0, 0, 0);
            float csum = 0.f;
#pragma unroll
            for (int mt = 0; mt < 4; ++mt)
#pragma unroll
                for (int reg = 0; reg < 4; ++reg) {
                    float e = __builtin_amdgcn_exp2f(acc[mt][reg]);
                    s[mt * 4 + reg] += e;
                    csum += e;
                }
            c[nt] = csum;
        }

        // row sums: reduce over t (16 lanes within q-group) -> LDS
#pragma unroll
        for (int idx = 0; idx < 16; ++idx) {
            float v = s[idx];
            v += __shfl_xor(v, 1, 64);
            v += __shfl_xor(v, 2, 64);
            v += __shfl_xor(v, 4, 64);
            v += __shfl_xor(v, 8, 64);
            if (t == 0)
                atomicAdd(&red[(wave >> 1) * 64 + (idx >> 2) * 16 + q * 4 + (idx & 3)], v);
        }
        // col sums: reduce over q (xor 16,32) -> LDS
#pragma unroll
        for (int nt = 0; nt < 4; ++nt) {
            float v = c[nt];
            v += __shfl_xor(v, 16, 64);
            v += __shfl_xor(v, 32, 64);
            if (q == 0)
                atomicAdd(&red[128 + (wave & 1) * 64 + nt * 16 + t], v);
        }
        __syncthreads();
        if (threadIdx.x < 128) {
            atomicAdd(&S_row[i * 128 + threadIdx.x], red[threadIdx.x]);
        } else if (!diag) {
            atomicAdd(&S_row[j * 128 + (threadIdx.x & 127)], red[threadIdx.x]);
        }
    } else {
        int r = (bid - NSIM) * 4 + wave;      // 0..8191
        const float* h = (r < BATCH) ? (h_i + (size_t)r * LATENT)
                                     : (h_j + (size_t)(r - BATCH) * LATENT);
        const f32x4* h4 = (const f32x4*)h;
        const f32x4* w4 = (const f32x4*)W;
        float s = 0.f;
#pragma unroll
        for (int itr = 0; itr < 8; ++itr) {
            f32x4 av = h4[itr * 64 + lane];
            f32x4 wv = w4[itr * 64 + lane];
            s += av.x * wv.x + av.y * wv.y + av.z * wv.z + av.w * wv.w;
        }
        s = wave_reduce_sum(s);
        if (lane == 0) logits[r] = s + bb[0];
    }
}

// Single block: nnPU risk from logits+target, NT-Xent sum from
// S_row (minus exact diagonal dexp) + pos, weighted combine.
__global__ void k_final(const float* __restrict__ S_row, const float* __restrict__ pos,
                        const float* __restrict__ dexp, const float* __restrict__ logits,
                        const int* __restrict__ target,
                        const float* __restrict__ w_onnpu, float* __restrict__ out) {
    float nt_s = 0.f;
    for (int r = threadIdx.x; r < NROWS; r += 1024)
        nt_s += __logf(S_row[r] - dexp[r]) - pos[r];
    float v[8];
#pragma unroll
    for (int i = 0; i < 8; ++i) v[i] = 0.f;
    for (int r = threadIdx.x; r < BATCH; r += 1024) {
        float li = logits[r], lj = logits[BATCH + r];
        bool p = (target[r] == 1);
        float si_n = 1.f / (1.f + __expf(li));
        float si_p = 1.f / (1.f + __expf(-li));
        float sj_n = 1.f / (1.f + __expf(lj));
        float sj_p = 1.f / (1.f + __expf(-lj));
        v[0] += p ? 1.f : 0.f;
        v[1] += p ? 0.f : 1.f;
        v[2] += p ? si_n : 0.f;
        v[3] += p ? si_p : 0.f;
        v[4] += p ? 0.f : si_p;
        v[5] += p ? sj_n : 0.f;
        v[6] += p ? sj_p : 0.f;
        v[7] += p ? 0.f : sj_p;
    }
    __shared__ float red[16][9];
    int wave = threadIdx.x >> 6, lane = threadIdx.x & 63;
    nt_s = wave_reduce_sum(nt_s);
#pragma unroll
    for (int i = 0; i < 8; ++i) v[i] = wave_reduce_sum(v[i]);
    if (lane == 0) {
        red[wave][0] = nt_s;
#pragma unroll
        for (int i = 0; i < 8; ++i) red[wave][1 + i] = v[i];
    }
    __syncthreads();
    if (threadIdx.x == 0) {
        float t[9];
#pragma unroll
        for (int i = 0; i < 9; ++i) {
            float acc = 0.f;
#pragma unroll
            for (int wv = 0; wv < 16; ++wv) acc += red[wv][i];
            t[i] = acc;
        }
        float ntxent = t[0] / (float)NROWS;
        float np = fmaxf(1.f, t[1]), nu = fmaxf(1.f, t[2]);
        float pr_i = PRIOR_PRIMEc / np * t[3];
        float nr_i = (1.f - PRIOR_PRIMEc) / (nu * (1.f - PRIORc)) * t[5]
                   - (1.f - PRIOR_PRIMEc) * PRIORc / (np * (1.f - PRIORc)) * t[4];
        float li_loss = (nr_i < 0.f) ? -nr_i : (pr_i + nr_i);
        float pr_j = PRIOR_PRIMEc / np * t[6];
        float nr_j = (1.f - PRIOR_PRIMEc) / (nu * (1.f - PRIORc)) * t[8]
                   - (1.f - PRIOR_PRIMEc) * PRIORc / (np * (1.f - PRIORc)) * t[7];
        float lj_loss = (nr_j < 0.f) ? -nr_j : (pr_j + nr_j);
        float onnpu = 0.5f * (li_loss + lj_loss);
        float w = w_onnpu[0];
        out[0] = w * onnpu + (1.f - w) * ntxent;
    }
}

extern "C" void kernel_launch(void* const* d_in, const int* in_sizes, int n_in,
                              void* d_out, int out_size, void* d_ws, size_t ws_size,
                              hipStream_t stream) {
    const float* h_i = (const float*)d_in[0];
    const float* h_j = (const float*)d_in[1];
    const float* z_i = (const float*)d_in[2];
    const float* z_j = (const float*)d_in[3];
    const int* target = (const int*)d_in[4];
    const float* W = (const float*)d_in[5];
    const float* b = (const float*)d_in[6];
    const float* w_onnpu = (const float*)d_in[7];

    char* ws = (char*)d_ws;
    unsigned short* znb = (unsigned short*)ws;              // 2 MB swizzled bf16
    float* S_row  = (float*)(ws + 2097152);                 // 32 KB
    float* pos    = (float*)(ws + 2097152 + 32768);         // 32 KB
    float* logits = (float*)(ws + 2097152 + 65536);         // 32 KB
    float* dexp   = (float*)(ws + 2097152 + 98304);         // 32 KB
    float* out = (float*)d_out;

    k_zprep<<<1024, 256, 0, stream>>>(z_i, z_j, znb, pos, dexp, S_row);
    k_main<<<NSIM + 2048, 256, 0, stream>>>(znb, S_row, h_i, h_j, W, b, logits);
    k_final<<<1, 1024, 0, stream>>>(S_row, pos, dexp, logits, target, w_onnpu, out);
}